// Round 8
// baseline (188.751 us; speedup 1.0000x reference)
//
#include <hip/hip_runtime.h>
#include <math.h>

#define K_CODES 512
#define DIM 64
#define ROWS_PER_BLOCK 128   // old fallback kernel: 256 threads, 2 k-halves/row
#define BROWS 512            // fused kernel: 16 waves x 32 rows, grid = n/512

// ---------------------------------------------------------------------------
// Exact-arithmetic helpers (bit-match the verified round-1/2 kernels).
// ---------------------------------------------------------------------------
__device__ __forceinline__ float np_pairwise_sumsq(const float* v) {
#pragma clang fp contract(off)
    float p[DIM];
#pragma unroll
    for (int j = 0; j < DIM; ++j) p[j] = v[j] * v[j];
    float r[8];
#pragma unroll
    for (int a = 0; a < 8; ++a) r[a] = p[a];
#pragma unroll
    for (int i = 8; i < DIM; i += 8) {
#pragma unroll
        for (int a = 0; a < 8; ++a) r[a] = r[a] + p[i + a];
    }
    return ((r[0] + r[1]) + (r[2] + r[3])) + ((r[4] + r[5]) + (r[6] + r[7]));
}

__device__ __forceinline__ float np_dot8acc(const float* zr, const float* ck) {
#pragma clang fp contract(off)
    float a0 = 0.f, a1 = 0.f, a2 = 0.f, a3 = 0.f;
    float a4 = 0.f, a5 = 0.f, a6 = 0.f, a7 = 0.f;
#pragma unroll
    for (int j = 0; j < DIM; j += 8) {
        a0 = fmaf(zr[j + 0], ck[j + 0], a0);
        a1 = fmaf(zr[j + 1], ck[j + 1], a1);
        a2 = fmaf(zr[j + 2], ck[j + 2], a2);
        a3 = fmaf(zr[j + 3], ck[j + 3], a3);
        a4 = fmaf(zr[j + 4], ck[j + 4], a4);
        a5 = fmaf(zr[j + 5], ck[j + 5], a5);
        a6 = fmaf(zr[j + 6], ck[j + 6], a6);
        a7 = fmaf(zr[j + 7], ck[j + 7], a7);
    }
    return ((a0 + a1) + (a2 + a3)) + ((a4 + a5) + (a6 + a7));
}

// ---------------------------------------------------------------------------
// OLD KERNEL (verified, 176 us) — dispatch fallback if n_rows % 512 != 0.
// ---------------------------------------------------------------------------
__global__ __launch_bounds__(256, 4) void vq_argmin_gather(
    const float* __restrict__ z, const float* __restrict__ cb,
    float* __restrict__ out, int n_rows) {
#pragma clang fp contract(off)
    __shared__ float esq_lds[K_CODES];
    __shared__ float red_d[ROWS_PER_BLOCK];
    __shared__ int   red_b[ROWS_PER_BLOCK];
    __shared__ int   best_lds[ROWS_PER_BLOCK];

    const int t = threadIdx.x;
    const int tr  = t & (ROWS_PER_BLOCK - 1);
    const int row = blockIdx.x * ROWS_PER_BLOCK + tr;
    const int k0 = __builtin_amdgcn_readfirstlane((t >> 7) << 8);

    float zr[DIM];
    const float4* zp = (const float4*)(z + (size_t)row * DIM);
#pragma unroll
    for (int j = 0; j < DIM / 4; ++j) {
        float4 v = zp[j];
        zr[4 * j + 0] = v.x; zr[4 * j + 1] = v.y;
        zr[4 * j + 2] = v.z; zr[4 * j + 3] = v.w;
    }
#pragma unroll
    for (int j = 0; j < DIM; ++j) { asm volatile("" : "+v"(zr[j])); }

    for (int c = t; c < K_CODES; c += 256)
        esq_lds[c] = np_pairwise_sumsq(cb + (size_t)c * DIM);
    __syncthreads();

    const float zsq = np_pairwise_sumsq(zr);
    float dmin = INFINITY;
    int best = k0;
    const float* __restrict__ cbase = cb + (size_t)k0 * DIM;
#pragma unroll 2
    for (int kk = 0; kk < K_CODES / 2; ++kk) {
        const float dot = np_dot8acc(zr, cbase + (size_t)kk * DIM);
        const float tkv = zsq + esq_lds[k0 + kk];
        const float m = 2.0f * dot;
        const float d = tkv - m;
        if (d < dmin) { dmin = d; best = k0 + kk; }
    }
    if (t >= ROWS_PER_BLOCK) { red_d[tr] = dmin; red_b[tr] = best; }
    __syncthreads();
    if (t < ROWS_PER_BLOCK) {
        int b = (red_d[tr] < dmin) ? red_b[tr] : best;
        best_lds[tr] = b;
    }
    __syncthreads();

    const float4* cb4 = (const float4*)cb;
    float4* o = (float4*)out;
    const size_t out1_off = (size_t)n_rows * (DIM / 4);
    const size_t grow = (size_t)blockIdx.x * ROWS_PER_BLOCK * (DIM / 4);
#pragma unroll
    for (int i = t; i < ROWS_PER_BLOCK * (DIM / 4); i += 256) {
        const int r = i >> 4;
        const int j = i & 15;
        const float4 v = cb4[(size_t)best_lds[r] * (DIM / 4) + j];
        const size_t g = grow + (size_t)r * (DIM / 4) + j;
        o[g] = v;
        o[g + out1_off] = v;
    }
}

// ---------------------------------------------------------------------------
// FUSED MFMA PATH (round 8). r7 diagnosis: main stall-bound at 2 waves/SIMD
// (MfmaUtil 18.5 + VALU 38 + LDS + write, poorly overlapped); fixup kernel
// re-streamed the whole 128 KB codebook per flagged row (35k x 128 KB =
// 4.5 GB of cache traffic, 61.6 us). Fixes:
//   - 1024 threads (16 waves = 4 waves/SIMD, same 131 KB LDS image): each
//     wave runs r7's verified 32-row group body once. VGPR ~88 < 128 cap.
//   - B-fragment image + esq built IN-BLOCK from cb (prep kernel, workspace,
//     and 35k global flag atomics all eliminated).
//   - exact fixup fused as a block-local phase: lane-per-row batches of 64,
//     16 waves x 32 codes each, codebook streamed wave-uniform (scalar path)
//     ONCE per batch; LDS merge in code order. Bit-identical np arithmetic.
//   - single epilogue write (r7's 18 MB fixup rewrite disappears).
// Numerics (split, EPS, merge semantics) byte-identical to rounds 2-7
// (absmax = 0.0 on every run). EPS floor is the reference's own ulp(64)
// rounding grid; the 27% flag rate is a property of the near-bounded score
// distribution (dense near-min clustering), so flags are made cheap instead.
// ---------------------------------------------------------------------------
typedef __bf16 bfx8 __attribute__((ext_vector_type(8)));
typedef float  f32x4 __attribute__((ext_vector_type(4)));

#define EPS_GAP 3.0e-5f

// fp32 -> (hi bf16, lo bf16); x-hi exact (Sterbenz), lo = RN(residual).
__device__ __forceinline__ void split_bf16(float x, unsigned short& h, unsigned short& l) {
    unsigned int xb = __float_as_uint(x);
    unsigned int hb = (xb + 0x8000u) & 0xffff0000u;
    h = (unsigned short)(hb >> 16);
    float lf = x - __uint_as_float(hb);
    l = (unsigned short)((__float_as_uint(lf) + 0x8000u) >> 16);
}

// 1024 threads = 16 waves x 32 rows = 512 rows/block; grid = n_rows/512 = 256
// (1 block/CU, LDS-capped). waves_per_eu(4,4): truthful (16 waves/CU = 4/EU)
// -> VGPR cap 128, no allocator shrink incentive (r5/r7 proved ~88 live fits).
__global__ __launch_bounds__(1024)
__attribute__((amdgpu_waves_per_eu(4, 4))) void vq_fused(
    const float* __restrict__ z, const float* __restrict__ cb,
    float* __restrict__ out, int n_rows) {
#pragma clang fp contract(off)
    __shared__ unsigned short b_lds[K_CODES * DIM * 2];  // 131072 B (hi | lo)
    __shared__ float esq_lds[K_CODES];
    __shared__ int   best_lds[BROWS];
    __shared__ int   flaglist[BROWS];
    __shared__ float fd[16][64];
    __shared__ int   fk[16][64];
    __shared__ int   nflag;

    const int t = threadIdx.x;       // 0..1023
    const int wave = t >> 6;         // 0..15
    const int lane = t & 63;
    const int lg = lane >> 4;        // k-group / D-row group
    const int lr = lane & 15;        // A row within set / D col (code)
    const int rb = blockIdx.x * BROWS;
    const int wrb = rb + wave * 32;

    if (t == 0) nflag = 0;

    // --- Stage: build B-fragment image (verified prep layout) from cb. ---
    // slot id = (tile*2 + kstep)*64 + l; elem j = cb[tile*16+(l&15)][kstep*32+(l>>4)*8+j]
#pragma unroll
    for (int i = 0; i < 4; ++i) {
        const int id = t + i * 1024;               // 0..4095
        const int l = id & 63;
        const int s = (id >> 6) & 1;
        const int tile = id >> 7;
        const int code = tile * 16 + (l & 15);
        const int d0 = s * 32 + (l >> 4) * 8;
        const float* p = cb + (size_t)code * DIM + d0;
        float4 v0 = *(const float4*)p;
        float4 v1 = *(const float4*)(p + 4);
        float f[8] = {v0.x, v0.y, v0.z, v0.w, v1.x, v1.y, v1.z, v1.w};
        union { unsigned short u[8]; uint4 q; } H, L;
#pragma unroll
        for (int j = 0; j < 8; ++j) split_bf16(f[j], H.u[j], L.u[j]);
        *(uint4*)(b_lds + (size_t)id * 8) = H.q;
        *(uint4*)(b_lds + 32768 + (size_t)id * 8) = L.q;
    }
    if (t < K_CODES) esq_lds[t] = np_pairwise_sumsq(cb + (size_t)t * DIM);

    // --- A fragments (verified layout): row = wrb + RS*16 + lr, k = s*32+lg*8+j.
    bfx8 a_hi[2][2], a_lo[2][2];
#pragma unroll
    for (int RS = 0; RS < 2; ++RS) {
#pragma unroll
        for (int s = 0; s < 2; ++s) {
            const float* zp = z + (size_t)(wrb + RS * 16 + lr) * DIM + s * 32 + lg * 8;
            float4 v0 = *(const float4*)zp;
            float4 v1 = *(const float4*)(zp + 4);
            float f[8] = {v0.x, v0.y, v0.z, v0.w, v1.x, v1.y, v1.z, v1.w};
            union { unsigned short u[8]; bfx8 b; } H, L;
#pragma unroll
            for (int j = 0; j < 8; ++j) split_bf16(f[j], H.u[j], L.u[j]);
            a_hi[RS][s] = H.b;
            a_lo[RS][s] = L.b;
        }
    }
    __syncthreads();   // b_lds + esq_lds + nflag ready

    // --- MFMA scan (r7 group body, verbatim). ---
    float b1[2][4], b2[2][4];
    int   k1[2][4];
#pragma unroll
    for (int RS = 0; RS < 2; ++RS)
#pragma unroll
        for (int i = 0; i < 4; ++i) { b1[RS][i] = INFINITY; b2[RS][i] = INFINITY; k1[RS][i] = 0; }

    for (int tt = 0; tt < 32; ++tt) {
        const int s0 = ((tt * 2 + 0) * 64 + lane) * 8;
        const int s1 = ((tt * 2 + 1) * 64 + lane) * 8;
        bfx8 bh0 = *(const bfx8*)(b_lds + s0);
        bfx8 bh1 = *(const bfx8*)(b_lds + s1);
        bfx8 bl0 = *(const bfx8*)(b_lds + 32768 + s0);
        bfx8 bl1 = *(const bfx8*)(b_lds + 32768 + s1);

        f32x4 acc0 = {0.f, 0.f, 0.f, 0.f};
        f32x4 acc1 = {0.f, 0.f, 0.f, 0.f};
        acc0 = __builtin_amdgcn_mfma_f32_16x16x32_bf16(a_hi[0][0], bh0, acc0, 0, 0, 0);
        acc0 = __builtin_amdgcn_mfma_f32_16x16x32_bf16(a_hi[0][1], bh1, acc0, 0, 0, 0);
        acc0 = __builtin_amdgcn_mfma_f32_16x16x32_bf16(a_hi[0][0], bl0, acc0, 0, 0, 0);
        acc0 = __builtin_amdgcn_mfma_f32_16x16x32_bf16(a_hi[0][1], bl1, acc0, 0, 0, 0);
        acc0 = __builtin_amdgcn_mfma_f32_16x16x32_bf16(a_lo[0][0], bh0, acc0, 0, 0, 0);
        acc0 = __builtin_amdgcn_mfma_f32_16x16x32_bf16(a_lo[0][1], bh1, acc0, 0, 0, 0);
        acc1 = __builtin_amdgcn_mfma_f32_16x16x32_bf16(a_hi[1][0], bh0, acc1, 0, 0, 0);
        acc1 = __builtin_amdgcn_mfma_f32_16x16x32_bf16(a_hi[1][1], bh1, acc1, 0, 0, 0);
        acc1 = __builtin_amdgcn_mfma_f32_16x16x32_bf16(a_hi[1][0], bl0, acc1, 0, 0, 0);
        acc1 = __builtin_amdgcn_mfma_f32_16x16x32_bf16(a_hi[1][1], bl1, acc1, 0, 0, 0);
        acc1 = __builtin_amdgcn_mfma_f32_16x16x32_bf16(a_lo[1][0], bh0, acc1, 0, 0, 0);
        acc1 = __builtin_amdgcn_mfma_f32_16x16x32_bf16(a_lo[1][1], bh1, acc1, 0, 0, 0);

        const float ev = esq_lds[tt * 16 + lr];
        const int   kk = tt * 16 + lr;
#pragma unroll
        for (int i = 0; i < 4; ++i) {
            {
                float s = fmaf(-2.0f, acc0[i], ev);   // row-constant zsq dropped
                b2[0][i] = fminf(fmaxf(s, b1[0][i]), b2[0][i]);
                bool c = s < b1[0][i];
                b1[0][i] = c ? s : b1[0][i];
                k1[0][i] = c ? kk : k1[0][i];
            }
            {
                float s = fmaf(-2.0f, acc1[i], ev);
                b2[1][i] = fminf(fmaxf(s, b1[1][i]), b2[1][i]);
                bool c = s < b1[1][i];
                b1[1][i] = c ? s : b1[1][i];
                k1[1][i] = c ? kk : k1[1][i];
            }
        }
    }

    // Reduce (b1,k1,b2) across the 16 lanes of each D-row group.
#pragma unroll
    for (int m = 1; m <= 8; m <<= 1) {
#pragma unroll
        for (int RS = 0; RS < 2; ++RS) {
#pragma unroll
            for (int i = 0; i < 4; ++i) {
                float ob1 = __shfl_xor(b1[RS][i], m);
                int   ok1 = __shfl_xor(k1[RS][i], m);
                float ob2 = __shfl_xor(b2[RS][i], m);
                float nb2 = fminf(fmaxf(b1[RS][i], ob1), fminf(b2[RS][i], ob2));
                bool take = (ob1 < b1[RS][i]) || (ob1 == b1[RS][i] && ok1 < k1[RS][i]);
                b1[RS][i] = take ? ob1 : b1[RS][i];
                k1[RS][i] = take ? ok1 : k1[RS][i];
                b2[RS][i] = nb2;
            }
        }
    }

    // Publish; flag near-ties into the BLOCK-LOCAL list (no global atomics).
    if (lr == 0) {
#pragma unroll
        for (int RS = 0; RS < 2; ++RS) {
#pragma unroll
            for (int i = 0; i < 4; ++i) {
                const int rl = wave * 32 + RS * 16 + lg * 4 + i;
                best_lds[rl] = k1[RS][i];
                if (b2[RS][i] - b1[RS][i] <= EPS_GAP) {
                    int p = atomicAdd(&nflag, 1);
                    flaglist[p] = rl;
                }
            }
        }
    }
    __syncthreads();

    // --- Exact fixup phase: batches of 64 rows, lane-per-row; each wave
    // scans 32 codes (wave-uniform codebook rows -> scalar path, streamed
    // once per batch); LDS merge in code order preserves first-index argmin.
    // Bit-identical np arithmetic (same helpers, same op order).
    const int nf = nflag;
    for (int base = 0; base < nf; base += 64) {
        const bool active = (base + lane) < nf;
        const int rl = flaglist[active ? (base + lane) : base];
        const float* zp = z + (size_t)(rb + rl) * DIM;
        float zs[DIM];
#pragma unroll
        for (int j = 0; j < DIM / 4; ++j) {
            float4 v = ((const float4*)zp)[j];
            zs[4 * j + 0] = v.x; zs[4 * j + 1] = v.y;
            zs[4 * j + 2] = v.z; zs[4 * j + 3] = v.w;
        }
        const float zsq = np_pairwise_sumsq(zs);

        const int c0 = wave * 32;
        const float* cbase = cb + (size_t)c0 * DIM;
        float dmin = INFINITY;
        int bk = c0;
        for (int c = 0; c < 32; ++c) {
            const float dot = np_dot8acc(zs, cbase + (size_t)c * DIM);
            const float tkv = zsq + esq_lds[c0 + c];
            const float m2 = 2.0f * dot;
            const float d = tkv - m2;
            if (d < dmin) { dmin = d; bk = c0 + c; }
        }
        fd[wave][lane] = dmin;
        fk[wave][lane] = bk;
        __syncthreads();
        if (t < 64 && (base + t) < nf) {
            float d = fd[0][t];
            int   k = fk[0][t];
#pragma unroll
            for (int w = 1; w < 16; ++w) {
                float od = fd[w][t];
                int   ok = fk[w][t];
                bool take = (od < d) || (od == d && ok < k);
                d = take ? od : d;
                k = take ? ok : k;
            }
            best_lds[flaglist[base + t]] = k;
        }
        __syncthreads();
    }

    // --- Single epilogue: block-cooperative coalesced gather + dual write.
    const float4* cb4 = (const float4*)cb;
    float4* o = (float4*)out;
    const size_t out1_off = (size_t)n_rows * (DIM / 4);
    const size_t grow = (size_t)blockIdx.x * BROWS * (DIM / 4);
#pragma unroll
    for (int i = t; i < BROWS * (DIM / 4); i += 1024) {
        const int r = i >> 4;
        const int j = i & 15;
        const float4 v = cb4[(size_t)best_lds[r] * (DIM / 4) + j];
        const size_t g = grow + (size_t)r * (DIM / 4) + j;
        o[g] = v;
        o[g + out1_off] = v;
    }
}

// ---------------------------------------------------------------------------
extern "C" void kernel_launch(void* const* d_in, const int* in_sizes, int n_in,
                              void* d_out, int out_size, void* d_ws, size_t ws_size,
                              hipStream_t stream) {
    const float* z  = (const float*)d_in[0];   // [N, 64] fp32
    const float* cb = (const float*)d_in[1];   // [512, 64] fp32
    float* out = (float*)d_out;                // [2 * N * 64] fp32

    const int n_rows = in_sizes[0] / DIM;      // 131072

    if ((n_rows % BROWS) == 0) {
        vq_fused<<<dim3(n_rows / BROWS), dim3(1024), 0, stream>>>(z, cb, out, n_rows);
    } else {
        vq_argmin_gather<<<dim3(n_rows / ROWS_PER_BLOCK), dim3(256), 0, stream>>>(
            z, cb, out, n_rows);
    }
}

// Round 9
// 169.641 us; speedup vs baseline: 1.1127x; 1.1127x over previous
//
#include <hip/hip_runtime.h>
#include <math.h>

#define K_CODES 512
#define DIM 64
#define ROWS_PER_BLOCK 128   // old fallback kernel: 256 threads, 2 k-halves/row
#define BROWS 512            // main: 16 waves x 32 rows; grid = n_rows/512

// ---------------------------------------------------------------------------
// Exact-arithmetic helpers (bit-match the verified round-1/2 kernels).
// ---------------------------------------------------------------------------
__device__ __forceinline__ float np_pairwise_sumsq(const float* v) {
#pragma clang fp contract(off)
    float p[DIM];
#pragma unroll
    for (int j = 0; j < DIM; ++j) p[j] = v[j] * v[j];
    float r[8];
#pragma unroll
    for (int a = 0; a < 8; ++a) r[a] = p[a];
#pragma unroll
    for (int i = 8; i < DIM; i += 8) {
#pragma unroll
        for (int a = 0; a < 8; ++a) r[a] = r[a] + p[i + a];
    }
    return ((r[0] + r[1]) + (r[2] + r[3])) + ((r[4] + r[5]) + (r[6] + r[7]));
}

__device__ __forceinline__ float np_dot8acc(const float* zr, const float* ck) {
#pragma clang fp contract(off)
    float a0 = 0.f, a1 = 0.f, a2 = 0.f, a3 = 0.f;
    float a4 = 0.f, a5 = 0.f, a6 = 0.f, a7 = 0.f;
#pragma unroll
    for (int j = 0; j < DIM; j += 8) {
        a0 = fmaf(zr[j + 0], ck[j + 0], a0);
        a1 = fmaf(zr[j + 1], ck[j + 1], a1);
        a2 = fmaf(zr[j + 2], ck[j + 2], a2);
        a3 = fmaf(zr[j + 3], ck[j + 3], a3);
        a4 = fmaf(zr[j + 4], ck[j + 4], a4);
        a5 = fmaf(zr[j + 5], ck[j + 5], a5);
        a6 = fmaf(zr[j + 6], ck[j + 6], a6);
        a7 = fmaf(zr[j + 7], ck[j + 7], a7);
    }
    return ((a0 + a1) + (a2 + a3)) + ((a4 + a5) + (a6 + a7));
}

// ---------------------------------------------------------------------------
// OLD KERNEL (verified, 176 us) — dispatch fallback if ws too small.
// ---------------------------------------------------------------------------
__global__ __launch_bounds__(256, 4) void vq_argmin_gather(
    const float* __restrict__ z, const float* __restrict__ cb,
    float* __restrict__ out, int n_rows) {
#pragma clang fp contract(off)
    __shared__ float esq_lds[K_CODES];
    __shared__ float red_d[ROWS_PER_BLOCK];
    __shared__ int   red_b[ROWS_PER_BLOCK];
    __shared__ int   best_lds[ROWS_PER_BLOCK];

    const int t = threadIdx.x;
    const int tr  = t & (ROWS_PER_BLOCK - 1);
    const int row = blockIdx.x * ROWS_PER_BLOCK + tr;
    const int k0 = __builtin_amdgcn_readfirstlane((t >> 7) << 8);

    float zr[DIM];
    const float4* zp = (const float4*)(z + (size_t)row * DIM);
#pragma unroll
    for (int j = 0; j < DIM / 4; ++j) {
        float4 v = zp[j];
        zr[4 * j + 0] = v.x; zr[4 * j + 1] = v.y;
        zr[4 * j + 2] = v.z; zr[4 * j + 3] = v.w;
    }
#pragma unroll
    for (int j = 0; j < DIM; ++j) { asm volatile("" : "+v"(zr[j])); }

    for (int c = t; c < K_CODES; c += 256)
        esq_lds[c] = np_pairwise_sumsq(cb + (size_t)c * DIM);
    __syncthreads();

    const float zsq = np_pairwise_sumsq(zr);
    float dmin = INFINITY;
    int best = k0;
    const float* __restrict__ cbase = cb + (size_t)k0 * DIM;
#pragma unroll 2
    for (int kk = 0; kk < K_CODES / 2; ++kk) {
        const float dot = np_dot8acc(zr, cbase + (size_t)kk * DIM);
        const float tkv = zsq + esq_lds[k0 + kk];
        const float m = 2.0f * dot;
        const float d = tkv - m;
        if (d < dmin) { dmin = d; best = k0 + kk; }
    }
    if (t >= ROWS_PER_BLOCK) { red_d[tr] = dmin; red_b[tr] = best; }
    __syncthreads();
    if (t < ROWS_PER_BLOCK) {
        int b = (red_d[tr] < dmin) ? red_b[tr] : best;
        best_lds[tr] = b;
    }
    __syncthreads();

    const float4* cb4 = (const float4*)cb;
    float4* o = (float4*)out;
    const size_t out1_off = (size_t)n_rows * (DIM / 4);
    const size_t grow = (size_t)blockIdx.x * ROWS_PER_BLOCK * (DIM / 4);
#pragma unroll
    for (int i = t; i < ROWS_PER_BLOCK * (DIM / 4); i += 256) {
        const int r = i >> 4;
        const int j = i & 15;
        const float4 v = cb4[(size_t)best_lds[r] * (DIM / 4) + j];
        const size_t g = grow + (size_t)r * (DIM / 4) + j;
        o[g] = v;
        o[g + out1_off] = v;
    }
}

// ---------------------------------------------------------------------------
// MFMA PATH, round 9. r8's fused fixup re-broke the allocator (VGPR 64,
// +9 MB spill, 129 us) — per pre-commitment, fixup is split back out.
//   vq_main16: r8's main phase only (16 waves, in-block staging); flags go
//     to a global list; block 0 exports esq to ws. Live set ~88 < 128 cap.
//   vq_fixup3: lane-per-row (z in VGPRs), codebook streamed WAVE-UNIFORM
//     (scalar path) once per 64-row batch — 64x less codebook traffic than
//     r7's 45-us fixup (which re-read all 128 KB per row). Codes split 4
//     ways across waves, LDS merge in code order. Bit-identical arithmetic.
// Numerics (split, EPS=3e-5, merge) identical to rounds 5-8 (absmax 0.0).
// ---------------------------------------------------------------------------
typedef __bf16 bfx8 __attribute__((ext_vector_type(8)));
typedef float  f32x4 __attribute__((ext_vector_type(4)));

#define EPS_GAP 3.0e-5f

// fp32 -> (hi bf16, lo bf16); x-hi exact (Sterbenz), lo = RN(residual).
__device__ __forceinline__ void split_bf16(float x, unsigned short& h, unsigned short& l) {
    unsigned int xb = __float_as_uint(x);
    unsigned int hb = (xb + 0x8000u) & 0xffff0000u;
    h = (unsigned short)(hb >> 16);
    float lf = x - __uint_as_float(hb);
    l = (unsigned short)((__float_as_uint(lf) + 0x8000u) >> 16);
}

// Main: 1024 threads = 16 waves x 32 rows = 512 rows/block; grid = 256
// (1 block/CU, LDS-capped at 135 KB). waves_per_eu(4,4) truthful -> 128-reg
// cap; scan live set ~88 (proven r5/r7). No fixup phase -> no zs[64] poison.
__global__ __launch_bounds__(1024)
__attribute__((amdgpu_waves_per_eu(4, 4))) void vq_main16(
    const float* __restrict__ z, const float* __restrict__ cb,
    float* __restrict__ out,
    float* __restrict__ esq_ws, int* __restrict__ gcnt, int* __restrict__ grows,
    int n_rows) {
    __shared__ unsigned short b_lds[K_CODES * DIM * 2];  // 131072 B (hi | lo)
    __shared__ float esq_lds[K_CODES];
    __shared__ int   best_lds[BROWS];

    const int t = threadIdx.x;       // 0..1023
    const int wave = t >> 6;         // 0..15
    const int lane = t & 63;
    const int lg = lane >> 4;        // k-group / D-row group
    const int lr = lane & 15;        // A row within set / D col (code)
    const int rb = blockIdx.x * BROWS;
    const int wrb = rb + wave * 32;

    // --- Stage: build B-fragment image (verified prep layout) from cb. ---
#pragma unroll
    for (int i = 0; i < 4; ++i) {
        const int id = t + i * 1024;               // 0..4095
        const int l = id & 63;
        const int s = (id >> 6) & 1;
        const int tile = id >> 7;
        const int code = tile * 16 + (l & 15);
        const int d0 = s * 32 + (l >> 4) * 8;
        const float* p = cb + (size_t)code * DIM + d0;
        float4 v0 = *(const float4*)p;
        float4 v1 = *(const float4*)(p + 4);
        float f[8] = {v0.x, v0.y, v0.z, v0.w, v1.x, v1.y, v1.z, v1.w};
        union { unsigned short u[8]; uint4 q; } H, L;
#pragma unroll
        for (int j = 0; j < 8; ++j) split_bf16(f[j], H.u[j], L.u[j]);
        *(uint4*)(b_lds + (size_t)id * 8) = H.q;
        *(uint4*)(b_lds + 32768 + (size_t)id * 8) = L.q;
    }
    if (t < K_CODES) {
        const float e = np_pairwise_sumsq(cb + (size_t)t * DIM);
        esq_lds[t] = e;
        if (blockIdx.x == 0) esq_ws[t] = e;   // export for the fixup kernel
    }

    // --- A fragments (verified layout): row = wrb + RS*16 + lr, k = s*32+lg*8+j.
    bfx8 a_hi[2][2], a_lo[2][2];
#pragma unroll
    for (int RS = 0; RS < 2; ++RS) {
#pragma unroll
        for (int s = 0; s < 2; ++s) {
            const float* zp = z + (size_t)(wrb + RS * 16 + lr) * DIM + s * 32 + lg * 8;
            float4 v0 = *(const float4*)zp;
            float4 v1 = *(const float4*)(zp + 4);
            float f[8] = {v0.x, v0.y, v0.z, v0.w, v1.x, v1.y, v1.z, v1.w};
            union { unsigned short u[8]; bfx8 b; } H, L;
#pragma unroll
            for (int j = 0; j < 8; ++j) split_bf16(f[j], H.u[j], L.u[j]);
            a_hi[RS][s] = H.b;
            a_lo[RS][s] = L.b;
        }
    }
    __syncthreads();   // b_lds + esq_lds ready

    // --- MFMA scan (r7/r8 verified body, verbatim). ---
    float b1[2][4], b2[2][4];
    int   k1[2][4];
#pragma unroll
    for (int RS = 0; RS < 2; ++RS)
#pragma unroll
        for (int i = 0; i < 4; ++i) { b1[RS][i] = INFINITY; b2[RS][i] = INFINITY; k1[RS][i] = 0; }

    for (int tt = 0; tt < 32; ++tt) {
        const int s0 = ((tt * 2 + 0) * 64 + lane) * 8;
        const int s1 = ((tt * 2 + 1) * 64 + lane) * 8;
        bfx8 bh0 = *(const bfx8*)(b_lds + s0);
        bfx8 bh1 = *(const bfx8*)(b_lds + s1);
        bfx8 bl0 = *(const bfx8*)(b_lds + 32768 + s0);
        bfx8 bl1 = *(const bfx8*)(b_lds + 32768 + s1);

        f32x4 acc0 = {0.f, 0.f, 0.f, 0.f};
        f32x4 acc1 = {0.f, 0.f, 0.f, 0.f};
        acc0 = __builtin_amdgcn_mfma_f32_16x16x32_bf16(a_hi[0][0], bh0, acc0, 0, 0, 0);
        acc0 = __builtin_amdgcn_mfma_f32_16x16x32_bf16(a_hi[0][1], bh1, acc0, 0, 0, 0);
        acc0 = __builtin_amdgcn_mfma_f32_16x16x32_bf16(a_hi[0][0], bl0, acc0, 0, 0, 0);
        acc0 = __builtin_amdgcn_mfma_f32_16x16x32_bf16(a_hi[0][1], bl1, acc0, 0, 0, 0);
        acc0 = __builtin_amdgcn_mfma_f32_16x16x32_bf16(a_lo[0][0], bh0, acc0, 0, 0, 0);
        acc0 = __builtin_amdgcn_mfma_f32_16x16x32_bf16(a_lo[0][1], bh1, acc0, 0, 0, 0);
        acc1 = __builtin_amdgcn_mfma_f32_16x16x32_bf16(a_hi[1][0], bh0, acc1, 0, 0, 0);
        acc1 = __builtin_amdgcn_mfma_f32_16x16x32_bf16(a_hi[1][1], bh1, acc1, 0, 0, 0);
        acc1 = __builtin_amdgcn_mfma_f32_16x16x32_bf16(a_hi[1][0], bl0, acc1, 0, 0, 0);
        acc1 = __builtin_amdgcn_mfma_f32_16x16x32_bf16(a_hi[1][1], bl1, acc1, 0, 0, 0);
        acc1 = __builtin_amdgcn_mfma_f32_16x16x32_bf16(a_lo[1][0], bh0, acc1, 0, 0, 0);
        acc1 = __builtin_amdgcn_mfma_f32_16x16x32_bf16(a_lo[1][1], bh1, acc1, 0, 0, 0);

        const float ev = esq_lds[tt * 16 + lr];
        const int   kk = tt * 16 + lr;
#pragma unroll
        for (int i = 0; i < 4; ++i) {
            {
                float s = fmaf(-2.0f, acc0[i], ev);   // row-constant zsq dropped
                b2[0][i] = fminf(fmaxf(s, b1[0][i]), b2[0][i]);
                bool c = s < b1[0][i];
                b1[0][i] = c ? s : b1[0][i];
                k1[0][i] = c ? kk : k1[0][i];
            }
            {
                float s = fmaf(-2.0f, acc1[i], ev);
                b2[1][i] = fminf(fmaxf(s, b1[1][i]), b2[1][i]);
                bool c = s < b1[1][i];
                b1[1][i] = c ? s : b1[1][i];
                k1[1][i] = c ? kk : k1[1][i];
            }
        }
    }

    // Reduce (b1,k1,b2) across the 16 lanes of each D-row group.
#pragma unroll
    for (int m = 1; m <= 8; m <<= 1) {
#pragma unroll
        for (int RS = 0; RS < 2; ++RS) {
#pragma unroll
            for (int i = 0; i < 4; ++i) {
                float ob1 = __shfl_xor(b1[RS][i], m);
                int   ok1 = __shfl_xor(k1[RS][i], m);
                float ob2 = __shfl_xor(b2[RS][i], m);
                float nb2 = fminf(fmaxf(b1[RS][i], ob1), fminf(b2[RS][i], ob2));
                bool take = (ob1 < b1[RS][i]) || (ob1 == b1[RS][i] && ok1 < k1[RS][i]);
                b1[RS][i] = take ? ob1 : b1[RS][i];
                k1[RS][i] = take ? ok1 : k1[RS][i];
                b2[RS][i] = nb2;
            }
        }
    }

    // Publish; append near-ties to the GLOBAL fixup list (r7-proven pattern).
    if (lr == 0) {
#pragma unroll
        for (int RS = 0; RS < 2; ++RS) {
#pragma unroll
            for (int i = 0; i < 4; ++i) {
                const int rl = wave * 32 + RS * 16 + lg * 4 + i;
                best_lds[rl] = k1[RS][i];
                if (b2[RS][i] - b1[RS][i] <= EPS_GAP) {
                    int p = atomicAdd(gcnt, 1);
                    grows[p] = rb + rl;
                }
            }
        }
    }
    __syncthreads();

    // --- Epilogue: block-cooperative coalesced gather + dual write. ---
    const float4* cb4 = (const float4*)cb;
    float4* o = (float4*)out;
    const size_t out1_off = (size_t)n_rows * (DIM / 4);
    const size_t grow = (size_t)blockIdx.x * BROWS * (DIM / 4);
#pragma unroll
    for (int i = t; i < BROWS * (DIM / 4); i += 1024) {
        const int r = i >> 4;
        const int j = i & 15;
        const float4 v = cb4[(size_t)best_lds[r] * (DIM / 4) + j];
        const size_t g = grow + (size_t)r * (DIM / 4) + j;
        o[g] = v;
        o[g + out1_off] = v;
    }
}

// Fixup v3: 256 thr = 4 waves; each block re-solves 64 flagged rows.
// lane-per-row: z row in VGPRs (zs[64]); codebook + esq streamed
// WAVE-UNIFORM (readfirstlane-forced scalar path, r5-7-proven) -> the
// 128 KB codebook is read once per 64 rows instead of once per row.
// Codes split 4 ways across waves; LDS merge in ascending code order
// preserves first-index argmin. Bit-identical np arithmetic.
__global__ __launch_bounds__(256, 1) void vq_fixup3(
    const float* __restrict__ z, const float* __restrict__ cb,
    const float* __restrict__ esq_g,
    const int* __restrict__ gcnt, const int* __restrict__ grows,
    float* __restrict__ out, int n_rows) {
#pragma clang fp contract(off)
    __shared__ float fd[4][64];
    __shared__ int   fk[4][64];
    __shared__ int   rowbuf[64];
    __shared__ int   bestk[64];

    const int t = threadIdx.x;
    const int w = t >> 6;        // wave 0..3
    const int lane = t & 63;
    const int nf = gcnt[0];

    for (int base = blockIdx.x * 64; base < nf; base += gridDim.x * 64) {
        const int nvalid = min(64, nf - base);
        if (t < 64) rowbuf[t] = grows[base + min(t, nvalid - 1)];
        __syncthreads();

        // per-lane z row (64 VGPRs; launch_bounds(256,1) -> 512-reg budget,
        // the config that held VGPR=256 spill-free in rounds 5-7)
        const int row = rowbuf[lane];
        float zs[DIM];
        const float4* zp = (const float4*)(z + (size_t)row * DIM);
#pragma unroll
        for (int j = 0; j < DIM / 4; ++j) {
            float4 v = zp[j];
            zs[4 * j + 0] = v.x; zs[4 * j + 1] = v.y;
            zs[4 * j + 2] = v.z; zs[4 * j + 3] = v.w;
        }
        const float zsq = np_pairwise_sumsq(zs);

        // wave-uniform code slice: codes c0..c0+127 streamed via scalar loads
        const int c0 = __builtin_amdgcn_readfirstlane(w * 128);
        const float* cbase = cb + (size_t)c0 * DIM;
        float dmin = INFINITY;
        int bk = c0;
        for (int c = 0; c < 128; ++c) {
            const float dot = np_dot8acc(zs, cbase + (size_t)c * DIM);
            const float tkv = zsq + esq_g[c0 + c];
            const float m2 = 2.0f * dot;
            const float d = tkv - m2;
            if (d < dmin) { dmin = d; bk = c0 + c; }
        }
        fd[w][lane] = dmin;
        fk[w][lane] = bk;
        __syncthreads();

        // merge the 4 wave-slices in ascending code order (first-index ties)
        if (t < 64) {
            float d = fd[0][t];
            int   k = fk[0][t];
#pragma unroll
            for (int ww = 1; ww < 4; ++ww) {
                float od = fd[ww][t];
                int   ok = fk[ww][t];
                bool take = (od < d) || (od == d && ok < k);
                d = take ? od : d;
                k = take ? ok : k;
            }
            bestk[t] = k;
        }
        __syncthreads();

        // cooperative overwrite of both output copies for the valid rows
        const float4* cb4 = (const float4*)cb;
        float4* o = (float4*)out;
        const size_t out1_off = (size_t)n_rows * (DIM / 4);
        for (int i = t; i < 64 * (DIM / 4); i += 256) {
            const int r = i >> 4;
            const int j = i & 15;
            if (r < nvalid) {
                const float4 v = cb4[(size_t)bestk[r] * (DIM / 4) + j];
                const size_t g = (size_t)rowbuf[r] * (DIM / 4) + j;
                o[g] = v;
                o[g + out1_off] = v;
            }
        }
        __syncthreads();
    }
}

// ---------------------------------------------------------------------------
extern "C" void kernel_launch(void* const* d_in, const int* in_sizes, int n_in,
                              void* d_out, int out_size, void* d_ws, size_t ws_size,
                              hipStream_t stream) {
    const float* z  = (const float*)d_in[0];   // [N, 64] fp32
    const float* cb = (const float*)d_in[1];   // [512, 64] fp32
    float* out = (float*)d_out;                // [2 * N * 64] fp32

    const int n_rows = in_sizes[0] / DIM;      // 131072

    // ws layout: gcnt int[4] | esq float[512] | grows int[n_rows]
    const size_t WS_NEED = 16 + K_CODES * 4 + (size_t)n_rows * 4;
    if (ws_size >= WS_NEED && (n_rows % BROWS) == 0) {
        int* gcnt = (int*)d_ws;
        float* esq = (float*)(gcnt + 4);
        int* grows = (int*)(esq + K_CODES);
        hipMemsetAsync(gcnt, 0, 4, stream);
        vq_main16<<<dim3(n_rows / BROWS), dim3(1024), 0, stream>>>(
            z, cb, out, esq, gcnt, grows, n_rows);
        vq_fixup3<<<dim3(1024), dim3(256), 0, stream>>>(
            z, cb, esq, gcnt, grows, out, n_rows);
    } else {
        vq_argmin_gather<<<dim3(n_rows / ROWS_PER_BLOCK), dim3(256), 0, stream>>>(
            z, cb, out, n_rows);
    }
}

// Round 11
// 163.471 us; speedup vs baseline: 1.1546x; 1.0377x over previous
//
#include <hip/hip_runtime.h>
#include <math.h>

#define K_CODES 512
#define DIM 64
#define ROWS_PER_BLOCK 128   // old fallback kernel: 256 threads, 2 k-halves/row
#define BROWS 512            // fused: 16 waves x 32 rows; grid = n_rows/512

// ---------------------------------------------------------------------------
// Exact-arithmetic helpers (bit-match the verified round-1/2 kernels).
// ---------------------------------------------------------------------------
__device__ __forceinline__ float np_pairwise_sumsq(const float* v) {
#pragma clang fp contract(off)
    float p[DIM];
#pragma unroll
    for (int j = 0; j < DIM; ++j) p[j] = v[j] * v[j];
    float r[8];
#pragma unroll
    for (int a = 0; a < 8; ++a) r[a] = p[a];
#pragma unroll
    for (int i = 8; i < DIM; i += 8) {
#pragma unroll
        for (int a = 0; a < 8; ++a) r[a] = r[a] + p[i + a];
    }
    return ((r[0] + r[1]) + (r[2] + r[3])) + ((r[4] + r[5]) + (r[6] + r[7]));
}

// Chunked form, BIT-IDENTICAL to np_pairwise_sumsq: same per-element squares
// (rounded individually, contract off), same accumulation sequence
// r[a]=p[a]; r[a]+=p[8k+a]; same tree combine — but only ~16 live regs
// (used in the fused fixup phase to avoid a 64-wide register spike).
__device__ __forceinline__ float np_pairwise_sumsq_chunked(const float* v) {
#pragma clang fp contract(off)
    float r[8];
#pragma unroll
    for (int a = 0; a < 8; ++a) r[a] = v[a] * v[a];
#pragma unroll
    for (int i = 8; i < DIM; i += 8) {
#pragma unroll
        for (int a = 0; a < 8; ++a) r[a] = r[a] + v[i + a] * v[i + a];
    }
    return ((r[0] + r[1]) + (r[2] + r[3])) + ((r[4] + r[5]) + (r[6] + r[7]));
}

__device__ __forceinline__ float np_dot8acc(const float* zr, const float* ck) {
#pragma clang fp contract(off)
    float a0 = 0.f, a1 = 0.f, a2 = 0.f, a3 = 0.f;
    float a4 = 0.f, a5 = 0.f, a6 = 0.f, a7 = 0.f;
#pragma unroll
    for (int j = 0; j < DIM; j += 8) {
        a0 = fmaf(zr[j + 0], ck[j + 0], a0);
        a1 = fmaf(zr[j + 1], ck[j + 1], a1);
        a2 = fmaf(zr[j + 2], ck[j + 2], a2);
        a3 = fmaf(zr[j + 3], ck[j + 3], a3);
        a4 = fmaf(zr[j + 4], ck[j + 4], a4);
        a5 = fmaf(zr[j + 5], ck[j + 5], a5);
        a6 = fmaf(zr[j + 6], ck[j + 6], a6);
        a7 = fmaf(zr[j + 7], ck[j + 7], a7);
    }
    return ((a0 + a1) + (a2 + a3)) + ((a4 + a5) + (a6 + a7));
}

// ---------------------------------------------------------------------------
// OLD KERNEL (verified, 176 us) — dispatch fallback if n_rows % 512 != 0.
// ---------------------------------------------------------------------------
__global__ __launch_bounds__(256, 4) void vq_argmin_gather(
    const float* __restrict__ z, const float* __restrict__ cb,
    float* __restrict__ out, int n_rows) {
#pragma clang fp contract(off)
    __shared__ float esq_lds[K_CODES];
    __shared__ float red_d[ROWS_PER_BLOCK];
    __shared__ int   red_b[ROWS_PER_BLOCK];
    __shared__ int   best_lds[ROWS_PER_BLOCK];

    const int t = threadIdx.x;
    const int tr  = t & (ROWS_PER_BLOCK - 1);
    const int row = blockIdx.x * ROWS_PER_BLOCK + tr;
    const int k0 = __builtin_amdgcn_readfirstlane((t >> 7) << 8);

    float zr[DIM];
    const float4* zp = (const float4*)(z + (size_t)row * DIM);
#pragma unroll
    for (int j = 0; j < DIM / 4; ++j) {
        float4 v = zp[j];
        zr[4 * j + 0] = v.x; zr[4 * j + 1] = v.y;
        zr[4 * j + 2] = v.z; zr[4 * j + 3] = v.w;
    }
#pragma unroll
    for (int j = 0; j < DIM; ++j) { asm volatile("" : "+v"(zr[j])); }

    for (int c = t; c < K_CODES; c += 256)
        esq_lds[c] = np_pairwise_sumsq(cb + (size_t)c * DIM);
    __syncthreads();

    const float zsq = np_pairwise_sumsq(zr);
    float dmin = INFINITY;
    int best = k0;
    const float* __restrict__ cbase = cb + (size_t)k0 * DIM;
#pragma unroll 2
    for (int kk = 0; kk < K_CODES / 2; ++kk) {
        const float dot = np_dot8acc(zr, cbase + (size_t)kk * DIM);
        const float tkv = zsq + esq_lds[k0 + kk];
        const float m = 2.0f * dot;
        const float d = tkv - m;
        if (d < dmin) { dmin = d; best = k0 + kk; }
    }
    if (t >= ROWS_PER_BLOCK) { red_d[tr] = dmin; red_b[tr] = best; }
    __syncthreads();
    if (t < ROWS_PER_BLOCK) {
        int b = (red_d[tr] < dmin) ? red_b[tr] : best;
        best_lds[tr] = b;
    }
    __syncthreads();

    const float4* cb4 = (const float4*)cb;
    float4* o = (float4*)out;
    const size_t out1_off = (size_t)n_rows * (DIM / 4);
    const size_t grow = (size_t)blockIdx.x * ROWS_PER_BLOCK * (DIM / 4);
#pragma unroll
    for (int i = t; i < ROWS_PER_BLOCK * (DIM / 4); i += 256) {
        const int r = i >> 4;
        const int j = i & 15;
        const float4 v = cb4[(size_t)best_lds[r] * (DIM / 4) + j];
        const size_t g = grow + (size_t)r * (DIM / 4) + j;
        o[g] = v;
        o[g + out1_off] = v;
    }
}

// ---------------------------------------------------------------------------
// FUSED MFMA PATH, round 11 (= round 10 + pragma placement fix).
// r9 counters: profiled nflag ~= 705 (WRITE 352.5 KB = 705 x 512 B); the
// earlier "35k" read came from replayed/re-poisoned profiling data (r7's
// 45-us fixup disproves 35k: that would need >=133 us of L2 traffic).
// r9's separate fixup kernel cost 60.6 us at ~1% occupancy (latency-bound
// serial s_load chains on ~11 active blocks). So: fuse the exact fixup into
// the main kernel, avoiding r8's register poison (per-lane zs[64]) by
// staging each flagged row's z into LDS and scanning wave-parallel
// (8 codes/lane, ~30 transient VGPRs). One dispatch; no ws, no memset.
// Numerics byte-identical to rounds 2-9 (absmax 0.0 on every passing run).
// ---------------------------------------------------------------------------
typedef __bf16 bfx8 __attribute__((ext_vector_type(8)));
typedef float  f32x4 __attribute__((ext_vector_type(4)));

#define EPS_GAP 3.0e-5f

// fp32 -> (hi bf16, lo bf16); x-hi exact (Sterbenz), lo = RN(residual).
__device__ __forceinline__ void split_bf16(float x, unsigned short& h, unsigned short& l) {
    unsigned int xb = __float_as_uint(x);
    unsigned int hb = (xb + 0x8000u) & 0xffff0000u;
    h = (unsigned short)(hb >> 16);
    float lf = x - __uint_as_float(hb);
    l = (unsigned short)((__float_as_uint(lf) + 0x8000u) >> 16);
}

// 1024 threads = 16 waves x 32 rows = 512 rows/block; grid = n_rows/512 = 256
// (1 block/CU, LDS-capped ~138 KB). waves_per_eu(4,4) truthful -> 128-reg cap;
// scan live ~88 (r5/r7/r9-proven), fixup-phase transients ~30.
__global__ __launch_bounds__(1024)
__attribute__((amdgpu_waves_per_eu(4, 4))) void vq_fused2(
    const float* __restrict__ z, const float* __restrict__ cb,
    float* __restrict__ out, int n_rows) {
    __shared__ unsigned short b_lds[K_CODES * DIM * 2];  // 131072 B (hi | lo)
    __shared__ float esq_lds[K_CODES];
    __shared__ int   best_lds[BROWS];
    __shared__ int   flag_lds[BROWS];
    __shared__ float zlds[16][DIM];
    __shared__ int   nflag;

    const int t = threadIdx.x;       // 0..1023
    const int wave = t >> 6;         // 0..15
    const int lane = t & 63;
    const int lg = lane >> 4;        // k-group / D-row group
    const int lr = lane & 15;        // A row within set / D col (code)
    const int rb = blockIdx.x * BROWS;
    const int wrb = rb + wave * 32;

    if (t == 0) nflag = 0;

    // --- Stage: build B-fragment image (verified prep layout) from cb. ---
#pragma unroll
    for (int i = 0; i < 4; ++i) {
        const int id = t + i * 1024;               // 0..4095
        const int l = id & 63;
        const int s = (id >> 6) & 1;
        const int tile = id >> 7;
        const int code = tile * 16 + (l & 15);
        const int d0 = s * 32 + (l >> 4) * 8;
        const float* p = cb + (size_t)code * DIM + d0;
        float4 v0 = *(const float4*)p;
        float4 v1 = *(const float4*)(p + 4);
        float f[8] = {v0.x, v0.y, v0.z, v0.w, v1.x, v1.y, v1.z, v1.w};
        union { unsigned short u[8]; uint4 q; } H, L;
#pragma unroll
        for (int j = 0; j < 8; ++j) split_bf16(f[j], H.u[j], L.u[j]);
        *(uint4*)(b_lds + (size_t)id * 8) = H.q;
        *(uint4*)(b_lds + 32768 + (size_t)id * 8) = L.q;
    }
    if (t < K_CODES) esq_lds[t] = np_pairwise_sumsq(cb + (size_t)t * DIM);

    // --- A fragments (verified layout): row = wrb + RS*16 + lr, k = s*32+lg*8+j.
    bfx8 a_hi[2][2], a_lo[2][2];
#pragma unroll
    for (int RS = 0; RS < 2; ++RS) {
#pragma unroll
        for (int s = 0; s < 2; ++s) {
            const float* zp = z + (size_t)(wrb + RS * 16 + lr) * DIM + s * 32 + lg * 8;
            float4 v0 = *(const float4*)zp;
            float4 v1 = *(const float4*)(zp + 4);
            float f[8] = {v0.x, v0.y, v0.z, v0.w, v1.x, v1.y, v1.z, v1.w};
            union { unsigned short u[8]; bfx8 b; } H, L;
#pragma unroll
            for (int j = 0; j < 8; ++j) split_bf16(f[j], H.u[j], L.u[j]);
            a_hi[RS][s] = H.b;
            a_lo[RS][s] = L.b;
        }
    }
    __syncthreads();   // b_lds + esq_lds + nflag ready

    // --- MFMA scan (r7/r9 verified body, verbatim). ---
    float b1[2][4], b2[2][4];
    int   k1[2][4];
#pragma unroll
    for (int RS = 0; RS < 2; ++RS)
#pragma unroll
        for (int i = 0; i < 4; ++i) { b1[RS][i] = INFINITY; b2[RS][i] = INFINITY; k1[RS][i] = 0; }

    for (int tt = 0; tt < 32; ++tt) {
        const int s0 = ((tt * 2 + 0) * 64 + lane) * 8;
        const int s1 = ((tt * 2 + 1) * 64 + lane) * 8;
        bfx8 bh0 = *(const bfx8*)(b_lds + s0);
        bfx8 bh1 = *(const bfx8*)(b_lds + s1);
        bfx8 bl0 = *(const bfx8*)(b_lds + 32768 + s0);
        bfx8 bl1 = *(const bfx8*)(b_lds + 32768 + s1);

        f32x4 acc0 = {0.f, 0.f, 0.f, 0.f};
        f32x4 acc1 = {0.f, 0.f, 0.f, 0.f};
        acc0 = __builtin_amdgcn_mfma_f32_16x16x32_bf16(a_hi[0][0], bh0, acc0, 0, 0, 0);
        acc0 = __builtin_amdgcn_mfma_f32_16x16x32_bf16(a_hi[0][1], bh1, acc0, 0, 0, 0);
        acc0 = __builtin_amdgcn_mfma_f32_16x16x32_bf16(a_hi[0][0], bl0, acc0, 0, 0, 0);
        acc0 = __builtin_amdgcn_mfma_f32_16x16x32_bf16(a_hi[0][1], bl1, acc0, 0, 0, 0);
        acc0 = __builtin_amdgcn_mfma_f32_16x16x32_bf16(a_lo[0][0], bh0, acc0, 0, 0, 0);
        acc0 = __builtin_amdgcn_mfma_f32_16x16x32_bf16(a_lo[0][1], bh1, acc0, 0, 0, 0);
        acc1 = __builtin_amdgcn_mfma_f32_16x16x32_bf16(a_hi[1][0], bh0, acc1, 0, 0, 0);
        acc1 = __builtin_amdgcn_mfma_f32_16x16x32_bf16(a_hi[1][1], bh1, acc1, 0, 0, 0);
        acc1 = __builtin_amdgcn_mfma_f32_16x16x32_bf16(a_hi[1][0], bl0, acc1, 0, 0, 0);
        acc1 = __builtin_amdgcn_mfma_f32_16x16x32_bf16(a_hi[1][1], bl1, acc1, 0, 0, 0);
        acc1 = __builtin_amdgcn_mfma_f32_16x16x32_bf16(a_lo[1][0], bh0, acc1, 0, 0, 0);
        acc1 = __builtin_amdgcn_mfma_f32_16x16x32_bf16(a_lo[1][1], bh1, acc1, 0, 0, 0);

        const float ev = esq_lds[tt * 16 + lr];
        const int   kk = tt * 16 + lr;
#pragma unroll
        for (int i = 0; i < 4; ++i) {
            {
                float s = fmaf(-2.0f, acc0[i], ev);   // row-constant zsq dropped
                b2[0][i] = fminf(fmaxf(s, b1[0][i]), b2[0][i]);
                bool c = s < b1[0][i];
                b1[0][i] = c ? s : b1[0][i];
                k1[0][i] = c ? kk : k1[0][i];
            }
            {
                float s = fmaf(-2.0f, acc1[i], ev);
                b2[1][i] = fminf(fmaxf(s, b1[1][i]), b2[1][i]);
                bool c = s < b1[1][i];
                b1[1][i] = c ? s : b1[1][i];
                k1[1][i] = c ? kk : k1[1][i];
            }
        }
    }

    // Reduce (b1,k1,b2) across the 16 lanes of each D-row group.
#pragma unroll
    for (int m = 1; m <= 8; m <<= 1) {
#pragma unroll
        for (int RS = 0; RS < 2; ++RS) {
#pragma unroll
            for (int i = 0; i < 4; ++i) {
                float ob1 = __shfl_xor(b1[RS][i], m);
                int   ok1 = __shfl_xor(k1[RS][i], m);
                float ob2 = __shfl_xor(b2[RS][i], m);
                float nb2 = fminf(fmaxf(b1[RS][i], ob1), fminf(b2[RS][i], ob2));
                bool take = (ob1 < b1[RS][i]) || (ob1 == b1[RS][i] && ok1 < k1[RS][i]);
                b1[RS][i] = take ? ob1 : b1[RS][i];
                k1[RS][i] = take ? ok1 : k1[RS][i];
                b2[RS][i] = nb2;
            }
        }
    }

    // Publish; flag near-ties into the block-local list.
    if (lr == 0) {
#pragma unroll
        for (int RS = 0; RS < 2; ++RS) {
#pragma unroll
            for (int i = 0; i < 4; ++i) {
                const int rl = wave * 32 + RS * 16 + lg * 4 + i;
                best_lds[rl] = k1[RS][i];
                if (b2[RS][i] - b1[RS][i] <= EPS_GAP) {
                    int p = atomicAdd(&nflag, 1);
                    flag_lds[p] = rl;
                }
            }
        }
    }
    __syncthreads();

    // --- Fused exact fixup: one flagged row per wave; z row staged in LDS
    // (no per-lane zs[64] -> no r8 register poison); 8 codes/lane with
    // per-lane vector cb loads; shfl-xor merge, first-index ties.
    // Arithmetic bit-identical to the verified exact path.
    const int nfl = nflag;
    for (int base = 0; base < nfl; base += 16) {
        const int idx = base + wave;
        if (idx < nfl) {
#pragma clang fp contract(off)
            const int rl = flag_lds[idx];              // wave-uniform
            const int row = rb + rl;
            if (lane < 16) {
                ((float4*)&zlds[wave][0])[lane] =
                    ((const float4*)(z + (size_t)row * DIM))[lane];
            }
            asm volatile("s_waitcnt lgkmcnt(0) vmcnt(0)" ::: "memory");
            const float* zp = (const float*)&zlds[wave][0];
            const float zsq = np_pairwise_sumsq_chunked(zp);
            float dmin = INFINITY;
            int bk = lane * 8;
            const float* cbase = cb + (size_t)(lane * 8) * DIM;
#pragma unroll
            for (int c = 0; c < 8; ++c) {
                const float dot = np_dot8acc(zp, cbase + (size_t)c * DIM);
                const float tkv = zsq + esq_lds[lane * 8 + c];
                const float m2 = 2.0f * dot;
                const float d = tkv - m2;
                if (d < dmin) { dmin = d; bk = lane * 8 + c; }
            }
#pragma unroll
            for (int m = 1; m <= 32; m <<= 1) {
                float od = __shfl_xor(dmin, m);
                int   ob = __shfl_xor(bk, m);
                bool take = (od < dmin) || (od == dmin && ob < bk);
                dmin = take ? od : dmin;
                bk = take ? ob : bk;
            }
            if (lane == 0) best_lds[rl] = bk;
        }
    }
    __syncthreads();

    // --- Single epilogue: block-cooperative coalesced gather + dual write.
    const float4* cb4 = (const float4*)cb;
    float4* o = (float4*)out;
    const size_t out1_off = (size_t)n_rows * (DIM / 4);
    const size_t grow = (size_t)blockIdx.x * BROWS * (DIM / 4);
#pragma unroll
    for (int i = t; i < BROWS * (DIM / 4); i += 1024) {
        const int r = i >> 4;
        const int j = i & 15;
        const float4 v = cb4[(size_t)best_lds[r] * (DIM / 4) + j];
        const size_t g = grow + (size_t)r * (DIM / 4) + j;
        o[g] = v;
        o[g + out1_off] = v;
    }
}

// ---------------------------------------------------------------------------
extern "C" void kernel_launch(void* const* d_in, const int* in_sizes, int n_in,
                              void* d_out, int out_size, void* d_ws, size_t ws_size,
                              hipStream_t stream) {
    const float* z  = (const float*)d_in[0];   // [N, 64] fp32
    const float* cb = (const float*)d_in[1];   // [512, 64] fp32
    float* out = (float*)d_out;                // [2 * N * 64] fp32

    const int n_rows = in_sizes[0] / DIM;      // 131072

    if ((n_rows % BROWS) == 0) {
        vq_fused2<<<dim3(n_rows / BROWS), dim3(1024), 0, stream>>>(z, cb, out, n_rows);
    } else {
        vq_argmin_gather<<<dim3(n_rows / ROWS_PER_BLOCK), dim3(256), 0, stream>>>(
            z, cb, out, n_rows);
    }
}